// Round 14
// baseline (532.265 us; speedup 1.0000x reference)
//
#include <hip/hip_runtime.h>
#include <math.h>
#include <stdint.h>

#define HIDN  2048
#define NH    16
#define DNOPE 128
#define DROPE 64
#define DQ    192
#define DV    128
#define QRANK 1536
#define KVRANK 512
#define SEQ   1024
#define NBATCH 2
#define NTOK  (NBATCH*SEQ)
#define EPSV  1e-6f

typedef unsigned short u16;
typedef unsigned int   u32;
typedef __attribute__((ext_vector_type(8))) short  short8;   // 8 bf16 (4 VGPRs)
typedef __attribute__((ext_vector_type(8))) unsigned short ushort8;
typedef __attribute__((ext_vector_type(4))) float  f32x4;

__device__ __forceinline__ u16 f2b(float f) {
    u32 u = __float_as_uint(f);
    u = (u + 0x7fffu + ((u >> 16) & 1u)) >> 16;   // RNE
    return (u16)u;
}
__device__ __forceinline__ float b2f(u16 h) {
    return __uint_as_float(((u32)h) << 16);
}

// async global->LDS, 16B per lane; LDS dest = wave-uniform base + lane*16
__device__ __forceinline__ void async_copy16(const u16* g, u16* l) {
    __builtin_amdgcn_global_load_lds(
        (const __attribute__((address_space(1))) u32*)g,
        (__attribute__((address_space(3))) u32*)l,
        16, 0, 0);
}

// LDS bank swizzle: slot for (row r, 16B-chunk c) = r*4 + (c ^ ((r>>1)&3)).
// Measured SQ_LDS_BANK_CONFLICT = 0 with this scheme.
__device__ __forceinline__ int swz(int r, int c) { return r * 4 + (c ^ ((r >> 1) & 3)); }

// ---------------------------------------------------------------------------
// VALU-only 16-lane-row reductions via DPP row_ror. Zero DS-pipe traffic.
// ---------------------------------------------------------------------------
#define DPP_ROR(x, ctrl) __int_as_float(__builtin_amdgcn_update_dpp( \
    __float_as_int(x), __float_as_int(x), ctrl, 0xF, 0xF, false))

__device__ __forceinline__ float rowmax16(float x) {
    x = fmaxf(x, DPP_ROR(x, 0x121));
    x = fmaxf(x, DPP_ROR(x, 0x122));
    x = fmaxf(x, DPP_ROR(x, 0x124));
    x = fmaxf(x, DPP_ROR(x, 0x128));
    return x;
}
__device__ __forceinline__ float rowsum16(float x) {
    x += DPP_ROR(x, 0x121);
    x += DPP_ROR(x, 0x122);
    x += DPP_ROR(x, 0x124);
    x += DPP_ROR(x, 0x128);
    return x;
}

// ---------------------------------------------------------------------------
// Fused cast fp32 -> bf16 over 10 segments, one dispatch. 8 elems/thread.
// RMSNorm ln-weight FOLD: seg 3 (q_b_w) cols scaled by q_a_ln_w[k],
// seg 4 (kv_b_w) by kv_a_ln_w[k].
// ---------------------------------------------------------------------------
struct CastArgs {
    const float* s[10];
    u16* d[10];
    int cum[11];
    const float* lnq;
    const float* lnkv;
};
__global__ __launch_bounds__(256)
void cast_all(CastArgs a, int total_chunks)
{
    int c = blockIdx.x * 256 + threadIdx.x;
    if (c >= total_chunks) return;
    int seg = 0;
    #pragma unroll
    for (int i = 1; i < 10; ++i) seg += (c >= a.cum[i]) ? 1 : 0;
    int local = c - a.cum[seg];
    const float* src = a.s[seg] + (size_t)local * 8;
    u16* dst = a.d[seg] + (size_t)local * 8;
    float4 x = *(const float4*)(src);
    float4 y = *(const float4*)(src + 4);
    if (seg == 3 || seg == 4) {
        const float* ln = (seg == 3) ? a.lnq : a.lnkv;
        u32 kmod = (seg == 3) ? (u32)QRANK : (u32)KVRANK;
        u32 kb = ((u32)local * 8u) % kmod;
        float4 w0 = *(const float4*)(ln + kb);
        float4 w1 = *(const float4*)(ln + kb + 4);
        x.x *= w0.x; x.y *= w0.y; x.z *= w0.z; x.w *= w0.w;
        y.x *= w1.x; y.y *= w1.y; y.z *= w1.z; y.w *= w1.w;
    }
    ushort8 o;
    o[0]=f2b(x.x); o[1]=f2b(x.y); o[2]=f2b(x.z); o[3]=f2b(x.w);
    o[4]=f2b(y.x); o[5]=f2b(y.y); o[6]=f2b(y.z); o[7]=f2b(y.w);
    *(ushort8*)(dst) = o;
}

// ---------------------------------------------------------------------------
// Multi-segment bf16 MFMA GEMM, 128x128 tile, BK=32, 4 waves, double-buffered
// global_load_lds staging, 2-way-free bank swizzle. Grid: x=token (fast),
// y=feature panel (slow). C = X[N x K] @ W[M x K]^T.
// modes: 5 bf16 flat + row-sumsq atomics; k_pe tiles (bn>=2048) do fused
//          k-RoPE straight into kf[...,128:192] |
//        1 qf head-major + inv_q scale + fused q-RoPE |
//        3 kv_b split + inv_kv scale |
//        7 sp token-major [b,h,s,128] store | 8 sp V^T [b,h,d,SEQ] store |
//        6 gate-scaled fp32 plain store (o-proj)
// Dispatch split along the dependency edge for load balance (R14):
//   A = [amid | sp_q | sp_k] (needs only Xb) = 56 panels, 3.5 blk/CU
//   B = [sp_v | q_b | kv_b]  (q/kv need amid) = 72 panels, 4.5 blk/CU
// vs old 384-block amid (1.5/CU, half the CUs idle) + 1664-block mega
// (25%-full last residency round). sp_v moves to B so its pvt(=aw_b alias)
// write happens after A's amid seg finished reading aw_b.
// ---------------------------------------------------------------------------
struct GemmSeg {
    const u16* X; const u16* W;
    float* Cf; u16* Cb; u16* Cb2; u16* Cb3;
    int K; int ldx; int ldc; int mode; int bx0;
};
struct GemmArgs { GemmSeg seg[3]; int nseg; float* ssq; float* sskv;
                  const float2* gates; };

__global__ __launch_bounds__(256)
void gemm_multi(GemmArgs a)
{
    __shared__ __align__(16) u16 As[2 * 4096];
    __shared__ __align__(16) u16 Bs[2 * 4096];
    int s = 0;
    if (a.nseg > 1 && (int)blockIdx.y >= a.seg[1].bx0) s = 1;
    if (a.nseg > 2 && (int)blockIdx.y >= a.seg[2].bx0) s = 2;
    const GemmSeg g = a.seg[s];

    const int tid = threadIdx.x;
    const int bn = ((int)blockIdx.y - g.bx0) * 128;   // feature base (slow dim)
    const int bm = blockIdx.x * 128;                  // token base (fast dim)
    const int lane = tid & 63, wv = tid >> 6;
    const int lm = lane & 15, lq = lane >> 4;
    const int wm = (wv >> 1) * 64, wn = (wv & 1) * 64;
    const int ldx = g.ldx, K = g.K;
    const u16* Xp = g.X;
    const u16* Wp = g.W;

    auto stage = [&](int kt, int buf) {
        int k0 = kt * 32;
        #pragma unroll
        for (int it = 0; it < 2; ++it) {
            int base = wv * 64 + it * 256;            // wave-uniform chunk base
            int slot = base + lane;
            int r = slot >> 2, c = (slot & 3) ^ ((r >> 1) & 3);   // swizzle inverse
            async_copy16(Xp + (size_t)(bm + r) * ldx + k0 + c * 8,
                         As + buf * 4096 + base * 8);
            async_copy16(Wp + (size_t)(bn + r) * K + k0 + c * 8,
                         Bs + buf * 4096 + base * 8);
        }
    };

    f32x4 acc[4][4] = {};
    const int niter = K >> 5;
    stage(0, 0);
    for (int kt = 0; kt < niter; ++kt) {
        int cur = kt & 1;
        __syncthreads();                 // drains stage(kt); frees other buffer
        if (kt + 1 < niter) stage(kt + 1, cur ^ 1);   // overlaps compute below
        const u16* Ab = As + cur * 4096;
        const u16* Bb = Bs + cur * 4096;
        short8 af[4], bf[4];
        #pragma unroll
        for (int mt = 0; mt < 4; ++mt) {
            int R = wm + mt * 16 + lm;
            af[mt] = *(const short8*)(Ab + swz(R, lq) * 8);
        }
        #pragma unroll
        for (int nt = 0; nt < 4; ++nt) {
            int R = wn + nt * 16 + lm;
            bf[nt] = *(const short8*)(Bb + swz(R, lq) * 8);
        }
        #pragma unroll
        for (int mt = 0; mt < 4; ++mt)
            #pragma unroll
            for (int nt = 0; nt < 4; ++nt)
                acc[mt][nt] = __builtin_amdgcn_mfma_f32_16x16x32_bf16(
                    af[mt], bf[nt], acc[mt][nt], 0, 0, 0);
    }

    // epilogue: C/D layout col=lane&15, row=(lane>>4)*4+i  [m89-verified]
    const int mode = g.mode;
    if (mode == 1) {
        // qf head-major, inv_q row-scale + fused RoPE (rope half iff hd0==128)
        const int h2  = (bn + wn) / DQ;
        const int hd0 = (bn + wn) % DQ;
        const bool ropeH = (hd0 == 128);
        float invf0 = 0.f, invf1 = 0.f;
        if (ropeH) {
            invf0 = exp2f((float)lm * -0.41524101186f);        // 10000^(-i/32)
            invf1 = exp2f((float)(16 + lm) * -0.41524101186f);
        }
        #pragma unroll
        for (int mt = 0; mt < 4; ++mt) {
            int token0 = bm + wm + mt * 16 + lq * 4;
            #pragma unroll
            for (int i = 0; i < 4; ++i) {
                int tok = token0 + i;
                int b2 = tok >> 10, s2 = tok & (SEQ - 1);
                float inv = rsqrtf(a.ssq[tok] * (1.f / QRANK) + EPSV);
                u16* row = g.Cb + ((size_t)((b2 * NH + h2) * SEQ + s2)) * DQ + hd0;
                if (!ropeH) {
                    #pragma unroll
                    for (int nt = 0; nt < 4; ++nt)
                        row[nt * 16 + lm] = f2b(acc[mt][nt][i] * inv);
                } else {
                    float sn0, c0, sn1, c1;
                    sincosf((float)s2 * invf0, &sn0, &c0);
                    sincosf((float)s2 * invf1, &sn1, &c1);
                    float x10 = acc[mt][0][i] * inv, x20 = acc[mt][2][i] * inv;
                    float x11 = acc[mt][1][i] * inv, x21 = acc[mt][3][i] * inv;
                    row[lm]          = f2b(x10 * c0 - x20 * sn0);
                    row[32 + lm]     = f2b(x20 * c0 + x10 * sn0);
                    row[16 + lm]     = f2b(x11 * c1 - x21 * sn1);
                    row[48 + lm]     = f2b(x21 * c1 + x11 * sn1);
                }
            }
        }
        return;
    }
    if (mode == 5 && bn >= QRANK + KVRANK) {
        // k_pe tile: fused k-RoPE straight into kf[...,128:192]. The 64-col
        // wave-half (bn+wn-2048) is one head's DROPE block; pair (i, i+32) =
        // (nt, nt+2) in the same thread.
        const int h2 = (bn + wn - (QRANK + KVRANK)) >> 6;
        float invf0 = exp2f((float)lm * -0.41524101186f);
        float invf1 = exp2f((float)(16 + lm) * -0.41524101186f);
        #pragma unroll
        for (int mt = 0; mt < 4; ++mt) {
            int token0 = bm + wm + mt * 16 + lq * 4;
            #pragma unroll
            for (int i = 0; i < 4; ++i) {
                int tok = token0 + i;
                int b2 = tok >> 10, s2 = tok & (SEQ - 1);
                float sn0, c0, sn1, c1;
                sincosf((float)s2 * invf0, &sn0, &c0);
                sincosf((float)s2 * invf1, &sn1, &c1);
                float x10 = acc[mt][0][i], x20 = acc[mt][2][i];
                float x11 = acc[mt][1][i], x21 = acc[mt][3][i];
                u16* row = g.Cb2 + ((size_t)((b2 * NH + h2) * SEQ + s2)) * DQ + DNOPE;
                row[lm]      = f2b(x10 * c0 - x20 * sn0);
                row[32 + lm] = f2b(x20 * c0 + x10 * sn0);
                row[16 + lm] = f2b(x11 * c1 - x21 * sn1);
                row[48 + lm] = f2b(x21 * c1 + x11 * sn1);
            }
        }
        return;
    }
    #pragma unroll
    for (int mt = 0; mt < 4; ++mt) {
        int token0 = bm + wm + mt * 16 + lq * 4;
        #pragma unroll
        for (int i = 0; i < 4; ++i) {
            int tok = token0 + i;
            int b2 = tok >> 10, s2 = tok & (SEQ - 1);
            float invkv = 1.f, gv = 1.f;
            if (mode == 3) invkv = rsqrtf(a.sskv[tok] * (1.f / KVRANK) + EPSV);
            if (mode == 6) {
                float2 g2 = a.gates[tok];
                gv = (g.ldc == 0) ? g2.x : g2.y;
            }
            #pragma unroll
            for (int nt = 0; nt < 4; ++nt) {
                int feat = bn + wn + nt * 16 + lm;
                float v = acc[mt][nt][i];
                if (mode == 6) {
                    g.Cf[(size_t)tok * HIDN + feat] = gv * v;   // plain store
                } else if (mode == 5) {
                    g.Cb[(size_t)tok * g.ldc + feat] = f2b(v);
                } else if (mode == 3) {
                    v *= invkv;
                    int h2 = feat >> 8, c = feat & 255;
                    if (c < 128)
                        g.Cb[((size_t)((b2 * NH + h2) * SEQ + s2)) * DQ + c] = f2b(v);
                    else
                        g.Cb2[((size_t)((b2 * NH + h2) * 128 + (c - 128))) * SEQ + s2] = f2b(v);
                } else if (mode == 7) {  // sp token-major [b,h,s,128]
                    int h2 = feat >> 7, d = feat & 127;
                    g.Cb[((size_t)((b2 * NH + h2) * SEQ + s2)) * 128 + d] = f2b(v);
                } else {                 // mode 8: sp V^T [b,h,d,SEQ]
                    int h2 = feat >> 7, d = feat & 127;
                    g.Cb[((size_t)((b2 * NH + h2) * 128 + d)) * SEQ + s2] = f2b(v);
                }
            }
        }
    }
    // mode 5 (amid, bn<2048): accumulate per-token sum-of-squares.
    if (mode == 5) {
        float* ssp = (bn < QRANK) ? a.ssq : a.sskv;
        #pragma unroll
        for (int mt = 0; mt < 4; ++mt) {
            int token0 = bm + wm + mt * 16 + lq * 4;
            #pragma unroll
            for (int i = 0; i < 4; ++i) {
                float sq = 0.f;
                #pragma unroll
                for (int nt = 0; nt < 4; ++nt) {
                    float v = acc[mt][nt][i];
                    sq += v * v;
                }
                sq = rowsum16(sq);              // sum over lm (16 cols x 4 nt)
                if (lm == 0) atomicAdd(&ssp[token0 + i], sq);
            }
        }
    }
}

// ---------------------------------------------------------------------------
// Lean streaming combine: out += patout (gate scaling already applied in the
// o-proj epilogues). 50MB traffic, float4-vectorized, grid-stride.
// ---------------------------------------------------------------------------
__global__ __launch_bounds__(256)
void add_combine(float* __restrict__ out, const float* __restrict__ patout)
{
    const int n4 = NTOK * HIDN / 4;   // 1M float4
    for (int i = blockIdx.x * 256 + threadIdx.x; i < n4; i += gridDim.x * 256) {
        float4 o = ((const float4*)out)[i];
        float4 q = ((const float4*)patout)[i];
        o.x += q.x; o.y += q.y; o.z += q.z; o.w += q.w;
        ((float4*)out)[i] = o;
    }
}

// ---------------------------------------------------------------------------
// Gate logits+softmax per token (tiny): gates[tok] = softmax(X@gw^T + gb)
// ---------------------------------------------------------------------------
__global__ __launch_bounds__(256)
void gate_kern(const float* __restrict__ x, const float* __restrict__ gw,
               const float* __restrict__ gb, float2* __restrict__ gates)
{
    const int tok = blockIdx.x;
    const float* xr = x + (size_t)tok * HIDN;
    float d0 = 0.f, d1 = 0.f;
    for (int i = threadIdx.x; i < HIDN; i += 256) {
        float v = xr[i];
        d0 += v * gw[i];
        d1 += v * gw[HIDN + i];
    }
    __shared__ float r0[256], r1[256];
    r0[threadIdx.x] = d0; r1[threadIdx.x] = d1;
    __syncthreads();
    for (int off = 128; off > 0; off >>= 1) {
        if (threadIdx.x < off) {
            r0[threadIdx.x] += r0[threadIdx.x + off];
            r1[threadIdx.x] += r1[threadIdx.x + off];
        }
        __syncthreads();
    }
    if (threadIdx.x == 0) {
        float l0 = r0[0] + gb[0], l1 = r1[0] + gb[1];
        float m = fmaxf(l0, l1);
        float e0 = __expf(l0 - m), e1 = __expf(l1 - m);
        float inv = 1.f / (e0 + e1);
        gates[tok] = make_float2(e0 * inv, e1 * inv);
    }
}

// ---------------------------------------------------------------------------
// MFMA flash attention body (V-STAGED; R12's V-direct regressed 21us).
// 32 q-rows per wave (rh=0,1); DPP softmax; defer-max (T13).
//   K: per-32k planes [ks][swizzled 32x4 chunks];  V: [swizzled 128x4 chunks]
// ---------------------------------------------------------------------------
template<int DQK>
__device__ __forceinline__
void flash_body(const u16* __restrict__ Q, const u16* __restrict__ Kf,
                const u16* __restrict__ Vt, u16* __restrict__ ctx_out,
                float scale, u16* Ks, u16* Vs, u16* Ps, int qt, int h, int bb)
{
    constexpr int KSZ  = 32 * DQK;    // u16 per K buffer
    constexpr int VSZ  = 32 * 128;    // u16 per V buffer
    constexpr int NKIT = DQK / 64;    // async calls per wave for K (3 or 2)
    constexpr int NT   = SEQ / 32;
    const int tid = threadIdx.x, lane = tid & 63, wv = tid >> 6;
    const int lm = lane & 15, lq = lane >> 4;
    const size_t bh = (size_t)bb * NH + h;
    const u16* Qb = Q + (bh * SEQ + qt * 128 + wv * 32) * (size_t)DQK;
    const u16* Kb = Kf + bh * SEQ * (size_t)DQK;
    const u16* Vb = Vt + bh * (size_t)128 * SEQ;

    short8 qfrag[2][DQK / 32];
    #pragma unroll
    for (int rh = 0; rh < 2; ++rh)
        #pragma unroll
        for (int ks = 0; ks < DQK / 32; ++ks)
            qfrag[rh][ks] = *(const short8*)(Qb + (rh * 16 + lm) * DQK + ks * 32 + lq * 8);

    auto stage = [&](int kt, int buf) {
        #pragma unroll
        for (int it = 0; it < NKIT; ++it) {
            int base = it * 256 + wv * 64;            // wave-uniform
            int slot = base + lane;
            int plane = slot >> 7, rem = slot & 127;
            int key = rem >> 2, c = (rem & 3) ^ ((key >> 1) & 3);  // swizzle inv
            async_copy16(Kb + (size_t)(kt * 32 + key) * DQK + plane * 32 + c * 8,
                         Ks + buf * KSZ + base * 8);
        }
        #pragma unroll
        for (int it = 0; it < 2; ++it) {
            int base = it * 256 + wv * 64;
            int slot = base + lane;
            int d = slot >> 2, c = (slot & 3) ^ ((d >> 1) & 3);    // swizzle inv
            async_copy16(Vb + (size_t)d * SEQ + kt * 32 + c * 8,
                         Vs + buf * VSZ + base * 8);
        }
    };

    float m_i[2][4], l_i[2][4];
    #pragma unroll
    for (int rh = 0; rh < 2; ++rh)
        #pragma unroll
        for (int i = 0; i < 4; ++i) { m_i[rh][i] = -INFINITY; l_i[rh][i] = 0.f; }
    f32x4 oacc[2][8] = {};

    stage(0, 0);
    for (int kt = 0; kt < NT; ++kt) {
        int cur = kt & 1;
        __syncthreads();                 // drains stage(kt); other buffer free
        if (kt + 1 < NT) stage(kt + 1, cur ^ 1);      // overlaps compute below
        const u16* Kc = Ks + cur * KSZ;
        const u16* Vc = Vs + cur * VSZ;

        // scores: S[rh][16x32] = Q(2x16xDQK) . K^T — kfr shared by both rh
        f32x4 sacc[2][2] = {};
        #pragma unroll
        for (int kb = 0; kb < 2; ++kb)
            #pragma unroll
            for (int ks = 0; ks < DQK / 32; ++ks) {
                int R = kb * 16 + lm;
                short8 kfr = *(const short8*)(Kc + ks * 1024 + swz(R, lq) * 8);
                sacc[0][kb] = __builtin_amdgcn_mfma_f32_16x16x32_bf16(
                    qfrag[0][ks], kfr, sacc[0][kb], 0, 0, 0);
                sacc[1][kb] = __builtin_amdgcn_mfma_f32_16x16x32_bf16(
                    qfrag[1][ks], kfr, sacc[1][kb], 0, 0, 0);
            }

        // online softmax with defer-max (rows = rh*16 + lq*4+i, cols = kb*16+lm)
        float p0[2][4], p1[2][4], mx[2][4];
        bool needb = false;
        #pragma unroll
        for (int rh = 0; rh < 2; ++rh)
            #pragma unroll
            for (int i = 0; i < 4; ++i) {
                float s0 = sacc[rh][0][i] * scale, s1 = sacc[rh][1][i] * scale;
                float m2 = rowmax16(fmaxf(s0, s1));   // DPP, VALU-only
                p0[rh][i] = s0; p1[rh][i] = s1; mx[rh][i] = m2;
                needb |= (m2 > m_i[rh][i] + 8.f);
            }
        bool need = __any(needb);
        float alpha[2][4];
        if (need) {
            #pragma unroll
            for (int rh = 0; rh < 2; ++rh)
                #pragma unroll
                for (int i = 0; i < 4; ++i) {
                    float mnew = fmaxf(m_i[rh][i], mx[rh][i]);
                    alpha[rh][i] = __expf(m_i[rh][i] - mnew);
                    m_i[rh][i] = mnew;
                    l_i[rh][i] *= alpha[rh][i];
                }
        }
        #pragma unroll
        for (int rh = 0; rh < 2; ++rh)
            #pragma unroll
            for (int i = 0; i < 4; ++i) {
                p0[rh][i] = __expf(p0[rh][i] - m_i[rh][i]);  // <= e^8 deferred
                p1[rh][i] = __expf(p1[rh][i] - m_i[rh][i]);
                l_i[rh][i] += rowsum16(p0[rh][i] + p1[rh][i]);   // DPP, VALU-only
            }

        // P: C-layout -> A-layout via per-wave LDS (wave-local, no barrier)
        u16* Pw = Ps + wv * 1280;
        #pragma unroll
        for (int rh = 0; rh < 2; ++rh)
            #pragma unroll
            for (int i = 0; i < 4; ++i) {
                Pw[(rh * 16 + lq * 4 + i) * 40 + lm]      = f2b(p0[rh][i]);
                Pw[(rh * 16 + lq * 4 + i) * 40 + 16 + lm] = f2b(p1[rh][i]);
            }
        short8 pfrag0 = *(const short8*)(Pw + lm * 40 + lq * 8);
        short8 pfrag1 = *(const short8*)(Pw + (16 + lm) * 40 + lq * 8);

        if (need) {
            #pragma unroll
            for (int rh = 0; rh < 2; ++rh)
                #pragma unroll
                for (int nt = 0; nt < 8; ++nt)
                    #pragma unroll
                    for (int i = 0; i < 4; ++i) oacc[rh][nt][i] *= alpha[rh][i];
        }
        // O += P . V  (8 col-tiles of 16) — vfr shared by both rh
        #pragma unroll
        for (int nt = 0; nt < 8; ++nt) {
            int R = nt * 16 + lm;
            short8 vfr = *(const short8*)(Vc + swz(R, lq) * 8);
            oacc[0][nt] = __builtin_amdgcn_mfma_f32_16x16x32_bf16(
                pfrag0, vfr, oacc[0][nt], 0, 0, 0);
            oacc[1][nt] = __builtin_amdgcn_mfma_f32_16x16x32_bf16(
                pfrag1, vfr, oacc[1][nt], 0, 0, 0);
        }
    }

    #pragma unroll
    for (int rh = 0; rh < 2; ++rh) {
        int s0 = qt * 128 + wv * 32 + rh * 16 + lq * 4;
        #pragma unroll
        for (int i = 0; i < 4; ++i) {
            float inv = 1.f / l_i[rh][i];
            u16* dst = ctx_out + ((size_t)(bb * SEQ + s0 + i) * NH + h) * 128;
            #pragma unroll
            for (int nt = 0; nt < 8; ++nt)
                dst[nt * 16 + lm] = f2b(oacc[rh][nt][i] * inv);
        }
    }
}

// Fused dual-branch flash. Grid (NH, 16, NBATCH): x=h so all q-tiles of a
// head land on one XCD. 512 blocks = exactly 2/CU.
__global__ __launch_bounds__(256, 2)
void flash_fused(const u16* qf, const u16* kf, const u16* Vtg, u16* ctx,
                 const u16* pq, const u16* pk, const u16* pvt, u16* p_ctx,
                 float scale_main, float scale_pat)
{
    __shared__ __align__(16) u16 Ks[2 * 32 * DQ];    // 24 KB
    __shared__ __align__(16) u16 Vs[2 * 32 * 128];   // 16 KB
    __shared__ __align__(16) u16 Ps[4 * 32 * 40];    // 10 KB
    int h = blockIdx.x, qtb = blockIdx.y, bb = blockIdx.z;
    if (qtb < 8)
        flash_body<DQ>(qf, kf, Vtg, ctx, scale_main, Ks, Vs, Ps, qtb, h, bb);
    else
        flash_body<128>(pq, pk, pvt, p_ctx, scale_pat, Ks, Vs, Ps, qtb - 8, h, bb);
}

// ---------------------------------------------------------------------------
extern "C" void kernel_launch(void* const* d_in, const int* in_sizes, int n_in,
                              void* d_out, int out_size, void* d_ws, size_t ws_size,
                              hipStream_t stream)
{
    const float* X        = (const float*)d_in[0];
    const float* q_a_w    = (const float*)d_in[1];
    const float* q_a_ln_w = (const float*)d_in[2];
    const float* q_b_w    = (const float*)d_in[3];
    const float* kv_a_w   = (const float*)d_in[4];
    const float* kv_a_ln_w= (const float*)d_in[5];
    const float* kv_b_w   = (const float*)d_in[6];
    const float* o_w      = (const float*)d_in[7];
    const float* sp_q_w   = (const float*)d_in[8];
    const float* sp_k_w   = (const float*)d_in[9];
    const float* sp_v_w   = (const float*)d_in[10];
    const float* sp_o_w   = (const float*)d_in[11];
    const float* gate_w   = (const float*)d_in[12];
    const float* gate_b   = (const float*)d_in[13];
    float* out = (float*)d_out;

    // workspace carve (256B aligned)
    char* p = (char*)d_ws;
    auto alloc = [&](size_t bytes) -> char* {
        char* r = p; p += (bytes + 255) & ~(size_t)255; return r;
    };
    u16* amid      = (u16*)alloc((size_t)NTOK * 3072 * 2);       // bf16 [tok][q_mid|kv_a]
    u16* Xb        = (u16*)alloc((size_t)NTOK * HIDN * 2);
    u16* aw_b      = (u16*)alloc((size_t)3072 * HIDN * 2);       // [q_a_w; kv_a_w]
    u16* q_b_wb    = (u16*)alloc((size_t)NH * DQ * QRANK * 2);
    u16* kv_b_wb   = (u16*)alloc((size_t)NH * 256 * KVRANK * 2);
    u16* o_wb      = (u16*)alloc((size_t)HIDN * HIDN * 2);
    u16* spqkv_wb  = (u16*)alloc((size_t)3 * HIDN * HIDN * 2);   // [spq;spk;spv]
    u16* sp_o_wb   = (u16*)alloc((size_t)HIDN * HIDN * 2);
    u16* qf        = (u16*)alloc((size_t)NTOK * NH * DQ * 2);
    u16* kf        = (u16*)alloc((size_t)NTOK * NH * DQ * 2);
    u16* Vtg       = (u16*)alloc((size_t)NBATCH * NH * 128 * SEQ * 2);
    u16* pq        = (u16*)alloc((size_t)NTOK * HIDN * 2);
    u16* pk        = (u16*)alloc((size_t)NTOK * HIDN * 2);
    float* ssbuf   = (float*)alloc((size_t)2 * NTOK * 4);        // [ss_q | ss_kv]
    float2* gates  = (float2*)alloc((size_t)NTOK * 8);
    // aliases (stream-ordered disjoint lifetimes):
    u16* pvt    = aw_b;          // aw_b dead after dispatch A; pvt written in B
    u16* ctx    = q_b_wb;        // q_b_wb dead after B; ctx written by flash
    u16* p_ctx  = spqkv_wb;      // spqkv_wb dead after B; written by flash
    float* patout = (float*)qf;  // qf+kf dead after flash; 16.8MB
    float* ss_q  = ssbuf;
    float* ss_kv = ssbuf + NTOK;

    dim3 blk(256);

    // ---- 0. zero the sum-of-squares accumulators (graph-capture safe) ----
    hipMemsetAsync(ssbuf, 0, (size_t)2 * NTOK * 4, stream);

    // ---- 1. single fused cast dispatch (ln weights folded into q_b/kv_b) ----
    CastArgs ca;
    const float* srcs[10] = {X, q_a_w, kv_a_w, q_b_w, kv_b_w, o_w,
                             sp_q_w, sp_k_w, sp_v_w, sp_o_w};
    u16* dsts[10] = {Xb, aw_b, aw_b + (size_t)QRANK * HIDN, q_b_wb, kv_b_wb, o_wb,
                     spqkv_wb, spqkv_wb + (size_t)HIDN * HIDN,
                     spqkv_wb + (size_t)2 * HIDN * HIDN, sp_o_wb};
    int ns[10] = {NTOK * HIDN, QRANK * HIDN, 1536 * HIDN, NH * DQ * QRANK,
                  NH * 256 * KVRANK, HIDN * HIDN, HIDN * HIDN, HIDN * HIDN,
                  HIDN * HIDN, HIDN * HIDN};
    int cum = 0;
    for (int i = 0; i < 10; ++i) {
        ca.s[i] = srcs[i]; ca.d[i] = dsts[i];
        ca.cum[i] = cum; cum += ns[i] / 8;
    }
    ca.cum[10] = cum;
    ca.lnq = q_a_ln_w; ca.lnkv = kv_a_ln_w;
    cast_all<<<dim3((cum + 255) / 256), blk, 0, stream>>>(ca, cum);

    // ---- 2. gate logits (only needs X; off the tail critical path) ----
    gate_kern<<<dim3(NTOK), blk, 0, stream>>>(X, gate_w, gate_b, gates);

    // ---- 3. dispatch A: amid (+sumsq, +k-rope->kf) | sp_q | sp_k ----
    //         all depend only on Xb; 56 panels = 896 blocks (3.5/CU)
    {
        GemmArgs ga = {};
        ga.nseg = 3;
        ga.seg[0] = {Xb, aw_b, nullptr, amid, kf, nullptr,
                     HIDN, HIDN, 3072, 5, 0};
        ga.seg[1] = {Xb, spqkv_wb, nullptr, pq, nullptr, nullptr,
                     HIDN, HIDN, 0, 7, 24};
        ga.seg[2] = {Xb, spqkv_wb + (size_t)HIDN * HIDN, nullptr, pk, nullptr, nullptr,
                     HIDN, HIDN, 0, 7, 40};
        ga.ssq = ss_q; ga.sskv = ss_kv;
        gemm_multi<<<dim3(16, 56), blk, 0, stream>>>(ga);
    }

    // ---- 4. dispatch B: sp_v (V^T; pvt=aw_b now dead) | q_b | kv_b ----
    //         72 panels = 1152 blocks (4.5/CU); longest-K first
    {
        GemmArgs ga = {};
        ga.nseg = 3;
        ga.seg[0] = {Xb, spqkv_wb + (size_t)2 * HIDN * HIDN, nullptr, pvt, nullptr, nullptr,
                     HIDN, HIDN, 0, 8, 0};
        ga.seg[1] = {amid, q_b_wb, nullptr, qf, nullptr, nullptr,
                     QRANK, 3072, 0, 1, 16};
        ga.seg[2] = {amid + QRANK, kv_b_wb, nullptr, kf, Vtg, nullptr,
                     KVRANK, 3072, 0, 3, 40};
        ga.ssq = ss_q; ga.sskv = ss_kv;
        gemm_multi<<<dim3(16, 72), blk, 0, stream>>>(ga);
    }

    // ---- 5. fused dual flash attention (512 blocks, 2/CU, XCD-aligned) ----
    flash_fused<<<dim3(NH, 16, NBATCH), blk, 0, stream>>>(
        qf, kf, Vtg, ctx, pq, pk, pvt, p_ctx,
        1.0f / sqrtf((float)DQ), 1.0f / sqrtf(128.0f));

    // ---- 6. o-proj (g0-scaled -> out) + sp_o-proj (g1-scaled -> patout),
    //         two independent segments, plain stores, 512 blocks = 2/CU ----
    {
        GemmArgs ga = {};
        ga.nseg = 2;
        ga.seg[0] = {ctx, o_wb, out, nullptr, nullptr, nullptr,
                     HIDN, HIDN, 0, 6, 0};
        ga.seg[1] = {p_ctx, sp_o_wb, patout, nullptr, nullptr, nullptr,
                     HIDN, HIDN, 1, 6, 16};
        ga.gates = gates;
        gemm_multi<<<dim3(16, 32), blk, 0, stream>>>(ga);
    }

    // ---- 7. lean streaming combine: out += patout (50MB, ~9us) ----
    add_combine<<<dim3(1024), blk, 0, stream>>>(out, patout);
}

// Round 15
// 522.749 us; speedup vs baseline: 1.0182x; 1.0182x over previous
//
#include <hip/hip_runtime.h>
#include <math.h>
#include <stdint.h>

#define HIDN  2048
#define NH    16
#define DNOPE 128
#define DROPE 64
#define DQ    192
#define DV    128
#define QRANK 1536
#define KVRANK 512
#define SEQ   1024
#define NBATCH 2
#define NTOK  (NBATCH*SEQ)
#define EPSV  1e-6f

typedef unsigned short u16;
typedef unsigned int   u32;
typedef __attribute__((ext_vector_type(8))) short  short8;   // 8 bf16 (4 VGPRs)
typedef __attribute__((ext_vector_type(8))) unsigned short ushort8;
typedef __attribute__((ext_vector_type(4))) float  f32x4;

__device__ __forceinline__ u16 f2b(float f) {
    u32 u = __float_as_uint(f);
    u = (u + 0x7fffu + ((u >> 16) & 1u)) >> 16;   // RNE
    return (u16)u;
}
__device__ __forceinline__ float b2f(u16 h) {
    return __uint_as_float(((u32)h) << 16);
}

// async global->LDS, 16B per lane; LDS dest = wave-uniform base + lane*16
__device__ __forceinline__ void async_copy16(const u16* g, u16* l) {
    __builtin_amdgcn_global_load_lds(
        (const __attribute__((address_space(1))) u32*)g,
        (__attribute__((address_space(3))) u32*)l,
        16, 0, 0);
}

// LDS bank swizzle: slot for (row r, 16B-chunk c) = r*4 + (c ^ ((r>>1)&3)).
// Measured SQ_LDS_BANK_CONFLICT = 0 with this scheme.
__device__ __forceinline__ int swz(int r, int c) { return r * 4 + (c ^ ((r >> 1) & 3)); }

// ---------------------------------------------------------------------------
// VALU-only 16-lane-row reductions via DPP row_ror. Zero DS-pipe traffic.
// ---------------------------------------------------------------------------
#define DPP_ROR(x, ctrl) __int_as_float(__builtin_amdgcn_update_dpp( \
    __float_as_int(x), __float_as_int(x), ctrl, 0xF, 0xF, false))

__device__ __forceinline__ float rowmax16(float x) {
    x = fmaxf(x, DPP_ROR(x, 0x121));
    x = fmaxf(x, DPP_ROR(x, 0x122));
    x = fmaxf(x, DPP_ROR(x, 0x124));
    x = fmaxf(x, DPP_ROR(x, 0x128));
    return x;
}
__device__ __forceinline__ float rowsum16(float x) {
    x += DPP_ROR(x, 0x121);
    x += DPP_ROR(x, 0x122);
    x += DPP_ROR(x, 0x124);
    x += DPP_ROR(x, 0x128);
    return x;
}

// ---------------------------------------------------------------------------
// Fused cast fp32 -> bf16 over 10 segments, one dispatch. 8 elems/thread.
// RMSNorm ln-weight FOLD: seg 3 (q_b_w) cols scaled by q_a_ln_w[k],
// seg 4 (kv_b_w) by kv_a_ln_w[k].
// ---------------------------------------------------------------------------
struct CastArgs {
    const float* s[10];
    u16* d[10];
    int cum[11];
    const float* lnq;
    const float* lnkv;
};
__global__ __launch_bounds__(256)
void cast_all(CastArgs a, int total_chunks)
{
    int c = blockIdx.x * 256 + threadIdx.x;
    if (c >= total_chunks) return;
    int seg = 0;
    #pragma unroll
    for (int i = 1; i < 10; ++i) seg += (c >= a.cum[i]) ? 1 : 0;
    int local = c - a.cum[seg];
    const float* src = a.s[seg] + (size_t)local * 8;
    u16* dst = a.d[seg] + (size_t)local * 8;
    float4 x = *(const float4*)(src);
    float4 y = *(const float4*)(src + 4);
    if (seg == 3 || seg == 4) {
        const float* ln = (seg == 3) ? a.lnq : a.lnkv;
        u32 kmod = (seg == 3) ? (u32)QRANK : (u32)KVRANK;
        u32 kb = ((u32)local * 8u) % kmod;
        float4 w0 = *(const float4*)(ln + kb);
        float4 w1 = *(const float4*)(ln + kb + 4);
        x.x *= w0.x; x.y *= w0.y; x.z *= w0.z; x.w *= w0.w;
        y.x *= w1.x; y.y *= w1.y; y.z *= w1.z; y.w *= w1.w;
    }
    ushort8 o;
    o[0]=f2b(x.x); o[1]=f2b(x.y); o[2]=f2b(x.z); o[3]=f2b(x.w);
    o[4]=f2b(y.x); o[5]=f2b(y.y); o[6]=f2b(y.z); o[7]=f2b(y.w);
    *(ushort8*)(dst) = o;
}

// ---------------------------------------------------------------------------
// Multi-segment bf16 MFMA GEMM, 128x128 tile, BK=32, 4 waves, double-buffered
// global_load_lds staging, 2-way-free bank swizzle. Grid: x=token (fast),
// y=feature panel (slow). C = X[N x K] @ W[M x K]^T.
// modes: 5 bf16 flat + row-sumsq atomics; k_pe tiles (bn>=2048) do fused
//          k-RoPE straight into kf[...,128:192] |
//        1 qf head-major + inv_q scale + fused q-RoPE |
//        3 kv_b split + inv_kv scale | 4 spqkv triple |
//        6 gate-scaled fp32 plain store (o-proj)
// R14 ledger: dispatch-split load balance was neutral (two 0.5-round tails +
// extra launch + Xb re-fetch == one 0.75-round tail). This single-mega
// structure is the best-measured configuration (526.0us R11 / 527.5 R13).
// ---------------------------------------------------------------------------
struct GemmSeg {
    const u16* X; const u16* W;
    float* Cf; u16* Cb; u16* Cb2; u16* Cb3;
    int K; int ldx; int ldc; int mode; int bx0;
};
struct GemmArgs { GemmSeg seg[3]; int nseg; float* ssq; float* sskv;
                  const float2* gates; };

__global__ __launch_bounds__(256)
void gemm_multi(GemmArgs a)
{
    __shared__ __align__(16) u16 As[2 * 4096];
    __shared__ __align__(16) u16 Bs[2 * 4096];
    int s = 0;
    if (a.nseg > 1 && (int)blockIdx.y >= a.seg[1].bx0) s = 1;
    if (a.nseg > 2 && (int)blockIdx.y >= a.seg[2].bx0) s = 2;
    const GemmSeg g = a.seg[s];

    const int tid = threadIdx.x;
    const int bn = ((int)blockIdx.y - g.bx0) * 128;   // feature base (slow dim)
    const int bm = blockIdx.x * 128;                  // token base (fast dim)
    const int lane = tid & 63, wv = tid >> 6;
    const int lm = lane & 15, lq = lane >> 4;
    const int wm = (wv >> 1) * 64, wn = (wv & 1) * 64;
    const int ldx = g.ldx, K = g.K;
    const u16* Xp = g.X;
    const u16* Wp = g.W;

    auto stage = [&](int kt, int buf) {
        int k0 = kt * 32;
        #pragma unroll
        for (int it = 0; it < 2; ++it) {
            int base = wv * 64 + it * 256;            // wave-uniform chunk base
            int slot = base + lane;
            int r = slot >> 2, c = (slot & 3) ^ ((r >> 1) & 3);   // swizzle inverse
            async_copy16(Xp + (size_t)(bm + r) * ldx + k0 + c * 8,
                         As + buf * 4096 + base * 8);
            async_copy16(Wp + (size_t)(bn + r) * K + k0 + c * 8,
                         Bs + buf * 4096 + base * 8);
        }
    };

    f32x4 acc[4][4] = {};
    const int niter = K >> 5;
    stage(0, 0);
    for (int kt = 0; kt < niter; ++kt) {
        int cur = kt & 1;
        __syncthreads();                 // drains stage(kt); frees other buffer
        if (kt + 1 < niter) stage(kt + 1, cur ^ 1);   // overlaps compute below
        const u16* Ab = As + cur * 4096;
        const u16* Bb = Bs + cur * 4096;
        short8 af[4], bf[4];
        #pragma unroll
        for (int mt = 0; mt < 4; ++mt) {
            int R = wm + mt * 16 + lm;
            af[mt] = *(const short8*)(Ab + swz(R, lq) * 8);
        }
        #pragma unroll
        for (int nt = 0; nt < 4; ++nt) {
            int R = wn + nt * 16 + lm;
            bf[nt] = *(const short8*)(Bb + swz(R, lq) * 8);
        }
        #pragma unroll
        for (int mt = 0; mt < 4; ++mt)
            #pragma unroll
            for (int nt = 0; nt < 4; ++nt)
                acc[mt][nt] = __builtin_amdgcn_mfma_f32_16x16x32_bf16(
                    af[mt], bf[nt], acc[mt][nt], 0, 0, 0);
    }

    // epilogue: C/D layout col=lane&15, row=(lane>>4)*4+i  [m89-verified]
    const int mode = g.mode;
    if (mode == 1) {
        // qf head-major, inv_q row-scale + fused RoPE (rope half iff hd0==128)
        const int h2  = (bn + wn) / DQ;
        const int hd0 = (bn + wn) % DQ;
        const bool ropeH = (hd0 == 128);
        float invf0 = 0.f, invf1 = 0.f;
        if (ropeH) {
            invf0 = exp2f((float)lm * -0.41524101186f);        // 10000^(-i/32)
            invf1 = exp2f((float)(16 + lm) * -0.41524101186f);
        }
        #pragma unroll
        for (int mt = 0; mt < 4; ++mt) {
            int token0 = bm + wm + mt * 16 + lq * 4;
            #pragma unroll
            for (int i = 0; i < 4; ++i) {
                int tok = token0 + i;
                int b2 = tok >> 10, s2 = tok & (SEQ - 1);
                float inv = rsqrtf(a.ssq[tok] * (1.f / QRANK) + EPSV);
                u16* row = g.Cb + ((size_t)((b2 * NH + h2) * SEQ + s2)) * DQ + hd0;
                if (!ropeH) {
                    #pragma unroll
                    for (int nt = 0; nt < 4; ++nt)
                        row[nt * 16 + lm] = f2b(acc[mt][nt][i] * inv);
                } else {
                    float sn0, c0, sn1, c1;
                    sincosf((float)s2 * invf0, &sn0, &c0);
                    sincosf((float)s2 * invf1, &sn1, &c1);
                    float x10 = acc[mt][0][i] * inv, x20 = acc[mt][2][i] * inv;
                    float x11 = acc[mt][1][i] * inv, x21 = acc[mt][3][i] * inv;
                    row[lm]          = f2b(x10 * c0 - x20 * sn0);
                    row[32 + lm]     = f2b(x20 * c0 + x10 * sn0);
                    row[16 + lm]     = f2b(x11 * c1 - x21 * sn1);
                    row[48 + lm]     = f2b(x21 * c1 + x11 * sn1);
                }
            }
        }
        return;
    }
    if (mode == 5 && bn >= QRANK + KVRANK) {
        // k_pe tile: fused k-RoPE straight into kf[...,128:192]. The 64-col
        // wave-half (bn+wn-2048) is one head's DROPE block; pair (i, i+32) =
        // (nt, nt+2) in the same thread. rope_k dispatch eliminated.
        const int h2 = (bn + wn - (QRANK + KVRANK)) >> 6;
        float invf0 = exp2f((float)lm * -0.41524101186f);
        float invf1 = exp2f((float)(16 + lm) * -0.41524101186f);
        #pragma unroll
        for (int mt = 0; mt < 4; ++mt) {
            int token0 = bm + wm + mt * 16 + lq * 4;
            #pragma unroll
            for (int i = 0; i < 4; ++i) {
                int tok = token0 + i;
                int b2 = tok >> 10, s2 = tok & (SEQ - 1);
                float sn0, c0, sn1, c1;
                sincosf((float)s2 * invf0, &sn0, &c0);
                sincosf((float)s2 * invf1, &sn1, &c1);
                float x10 = acc[mt][0][i], x20 = acc[mt][2][i];
                float x11 = acc[mt][1][i], x21 = acc[mt][3][i];
                u16* row = g.Cb2 + ((size_t)((b2 * NH + h2) * SEQ + s2)) * DQ + DNOPE;
                row[lm]      = f2b(x10 * c0 - x20 * sn0);
                row[32 + lm] = f2b(x20 * c0 + x10 * sn0);
                row[16 + lm] = f2b(x11 * c1 - x21 * sn1);
                row[48 + lm] = f2b(x21 * c1 + x11 * sn1);
            }
        }
        return;
    }
    #pragma unroll
    for (int mt = 0; mt < 4; ++mt) {
        int token0 = bm + wm + mt * 16 + lq * 4;
        #pragma unroll
        for (int i = 0; i < 4; ++i) {
            int tok = token0 + i;
            int b2 = tok >> 10, s2 = tok & (SEQ - 1);
            float invkv = 1.f, gv = 1.f;
            if (mode == 3) invkv = rsqrtf(a.sskv[tok] * (1.f / KVRANK) + EPSV);
            if (mode == 6) {
                float2 g2 = a.gates[tok];
                gv = (g.ldc == 0) ? g2.x : g2.y;
            }
            #pragma unroll
            for (int nt = 0; nt < 4; ++nt) {
                int feat = bn + wn + nt * 16 + lm;
                float v = acc[mt][nt][i];
                if (mode == 6) {
                    g.Cf[(size_t)tok * HIDN + feat] = gv * v;   // plain store
                } else if (mode == 5) {
                    g.Cb[(size_t)tok * g.ldc + feat] = f2b(v);
                } else if (mode == 3) {
                    v *= invkv;
                    int h2 = feat >> 8, c = feat & 255;
                    if (c < 128)
                        g.Cb[((size_t)((b2 * NH + h2) * SEQ + s2)) * DQ + c] = f2b(v);
                    else
                        g.Cb2[((size_t)((b2 * NH + h2) * 128 + (c - 128))) * SEQ + s2] = f2b(v);
                } else { // mode 4: spqkv
                    int wsel = feat >> 11;
                    int f2 = feat & 2047;
                    int h2 = f2 >> 7, d = f2 & 127;
                    if (wsel == 0)
                        g.Cb[((size_t)((b2 * NH + h2) * SEQ + s2)) * 128 + d] = f2b(v);
                    else if (wsel == 1)
                        g.Cb2[((size_t)((b2 * NH + h2) * SEQ + s2)) * 128 + d] = f2b(v);
                    else
                        g.Cb3[((size_t)((b2 * NH + h2) * 128 + d)) * SEQ + s2] = f2b(v);
                }
            }
        }
    }
    // mode 5 (amid, bn<2048): accumulate per-token sum-of-squares.
    if (mode == 5) {
        float* ssp = (bn < QRANK) ? a.ssq : a.sskv;
        #pragma unroll
        for (int mt = 0; mt < 4; ++mt) {
            int token0 = bm + wm + mt * 16 + lq * 4;
            #pragma unroll
            for (int i = 0; i < 4; ++i) {
                float sq = 0.f;
                #pragma unroll
                for (int nt = 0; nt < 4; ++nt) {
                    float v = acc[mt][nt][i];
                    sq += v * v;
                }
                sq = rowsum16(sq);              // sum over lm (16 cols x 4 nt)
                if (lm == 0) atomicAdd(&ssp[token0 + i], sq);
            }
        }
    }
}

// ---------------------------------------------------------------------------
// Lean streaming combine: out += patout (gate scaling already applied in the
// o-proj epilogues). 50MB traffic, float4-vectorized, grid-stride.
// ---------------------------------------------------------------------------
__global__ __launch_bounds__(256)
void add_combine(float* __restrict__ out, const float* __restrict__ patout)
{
    const int n4 = NTOK * HIDN / 4;   // 1M float4
    for (int i = blockIdx.x * 256 + threadIdx.x; i < n4; i += gridDim.x * 256) {
        float4 o = ((const float4*)out)[i];
        float4 q = ((const float4*)patout)[i];
        o.x += q.x; o.y += q.y; o.z += q.z; o.w += q.w;
        ((float4*)out)[i] = o;
    }
}

// ---------------------------------------------------------------------------
// Gate logits+softmax per token (tiny): gates[tok] = softmax(X@gw^T + gb)
// ---------------------------------------------------------------------------
__global__ __launch_bounds__(256)
void gate_kern(const float* __restrict__ x, const float* __restrict__ gw,
               const float* __restrict__ gb, float2* __restrict__ gates)
{
    const int tok = blockIdx.x;
    const float* xr = x + (size_t)tok * HIDN;
    float d0 = 0.f, d1 = 0.f;
    for (int i = threadIdx.x; i < HIDN; i += 256) {
        float v = xr[i];
        d0 += v * gw[i];
        d1 += v * gw[HIDN + i];
    }
    __shared__ float r0[256], r1[256];
    r0[threadIdx.x] = d0; r1[threadIdx.x] = d1;
    __syncthreads();
    for (int off = 128; off > 0; off >>= 1) {
        if (threadIdx.x < off) {
            r0[threadIdx.x] += r0[threadIdx.x + off];
            r1[threadIdx.x] += r1[threadIdx.x + off];
        }
        __syncthreads();
    }
    if (threadIdx.x == 0) {
        float l0 = r0[0] + gb[0], l1 = r1[0] + gb[1];
        float m = fmaxf(l0, l1);
        float e0 = __expf(l0 - m), e1 = __expf(l1 - m);
        float inv = 1.f / (e0 + e1);
        gates[tok] = make_float2(e0 * inv, e1 * inv);
    }
}

// ---------------------------------------------------------------------------
// MFMA flash attention body (V-STAGED; R12's V-direct regressed 21us: V loads
// joined the per-tile vmcnt(0) barrier drain with zero prefetch distance).
// 32 q-rows per wave (rh=0,1); DPP softmax; defer-max (T13).
//   K: per-32k planes [ks][swizzled 32x4 chunks];  V: [swizzled 128x4 chunks]
// ---------------------------------------------------------------------------
template<int DQK>
__device__ __forceinline__
void flash_body(const u16* __restrict__ Q, const u16* __restrict__ Kf,
                const u16* __restrict__ Vt, u16* __restrict__ ctx_out,
                float scale, u16* Ks, u16* Vs, u16* Ps, int qt, int h, int bb)
{
    constexpr int KSZ  = 32 * DQK;    // u16 per K buffer
    constexpr int VSZ  = 32 * 128;    // u16 per V buffer
    constexpr int NKIT = DQK / 64;    // async calls per wave for K (3 or 2)
    constexpr int NT   = SEQ / 32;
    const int tid = threadIdx.x, lane = tid & 63, wv = tid >> 6;
    const int lm = lane & 15, lq = lane >> 4;
    const size_t bh = (size_t)bb * NH + h;
    const u16* Qb = Q + (bh * SEQ + qt * 128 + wv * 32) * (size_t)DQK;
    const u16* Kb = Kf + bh * SEQ * (size_t)DQK;
    const u16* Vb = Vt + bh * (size_t)128 * SEQ;

    short8 qfrag[2][DQK / 32];
    #pragma unroll
    for (int rh = 0; rh < 2; ++rh)
        #pragma unroll
        for (int ks = 0; ks < DQK / 32; ++ks)
            qfrag[rh][ks] = *(const short8*)(Qb + (rh * 16 + lm) * DQK + ks * 32 + lq * 8);

    auto stage = [&](int kt, int buf) {
        #pragma unroll
        for (int it = 0; it < NKIT; ++it) {
            int base = it * 256 + wv * 64;            // wave-uniform
            int slot = base + lane;
            int plane = slot >> 7, rem = slot & 127;
            int key = rem >> 2, c = (rem & 3) ^ ((key >> 1) & 3);  // swizzle inv
            async_copy16(Kb + (size_t)(kt * 32 + key) * DQK + plane * 32 + c * 8,
                         Ks + buf * KSZ + base * 8);
        }
        #pragma unroll
        for (int it = 0; it < 2; ++it) {
            int base = it * 256 + wv * 64;
            int slot = base + lane;
            int d = slot >> 2, c = (slot & 3) ^ ((d >> 1) & 3);    // swizzle inv
            async_copy16(Vb + (size_t)d * SEQ + kt * 32 + c * 8,
                         Vs + buf * VSZ + base * 8);
        }
    };

    float m_i[2][4], l_i[2][4];
    #pragma unroll
    for (int rh = 0; rh < 2; ++rh)
        #pragma unroll
        for (int i = 0; i < 4; ++i) { m_i[rh][i] = -INFINITY; l_i[rh][i] = 0.f; }
    f32x4 oacc[2][8] = {};

    stage(0, 0);
    for (int kt = 0; kt < NT; ++kt) {
        int cur = kt & 1;
        __syncthreads();                 // drains stage(kt); other buffer free
        if (kt + 1 < NT) stage(kt + 1, cur ^ 1);      // overlaps compute below
        const u16* Kc = Ks + cur * KSZ;
        const u16* Vc = Vs + cur * VSZ;

        // scores: S[rh][16x32] = Q(2x16xDQK) . K^T — kfr shared by both rh
        f32x4 sacc[2][2] = {};
        #pragma unroll
        for (int kb = 0; kb < 2; ++kb)
            #pragma unroll
            for (int ks = 0; ks < DQK / 32; ++ks) {
                int R = kb * 16 + lm;
                short8 kfr = *(const short8*)(Kc + ks * 1024 + swz(R, lq) * 8);
                sacc[0][kb] = __builtin_amdgcn_mfma_f32_16x16x32_bf16(
                    qfrag[0][ks], kfr, sacc[0][kb], 0, 0, 0);
                sacc[1][kb] = __builtin_amdgcn_mfma_f32_16x16x32_bf16(
                    qfrag[1][ks], kfr, sacc[1][kb], 0, 0, 0);
            }

        // online softmax with defer-max (rows = rh*16 + lq*4+i, cols = kb*16+lm)
        float p0[2][4], p1[2][4], mx[2][4];
        bool needb = false;
        #pragma unroll
        for (int rh = 0; rh < 2; ++rh)
            #pragma unroll
            for (int i = 0; i < 4; ++i) {
                float s0 = sacc[rh][0][i] * scale, s1 = sacc[rh][1][i] * scale;
                float m2 = rowmax16(fmaxf(s0, s1));   // DPP, VALU-only
                p0[rh][i] = s0; p1[rh][i] = s1; mx[rh][i] = m2;
                needb |= (m2 > m_i[rh][i] + 8.f);
            }
        bool need = __any(needb);
        float alpha[2][4];
        if (need) {
            #pragma unroll
            for (int rh = 0; rh < 2; ++rh)
                #pragma unroll
                for (int i = 0; i < 4; ++i) {
                    float mnew = fmaxf(m_i[rh][i], mx[rh][i]);
                    alpha[rh][i] = __expf(m_i[rh][i] - mnew);
                    m_i[rh][i] = mnew;
                    l_i[rh][i] *= alpha[rh][i];
                }
        }
        #pragma unroll
        for (int rh = 0; rh < 2; ++rh)
            #pragma unroll
            for (int i = 0; i < 4; ++i) {
                p0[rh][i] = __expf(p0[rh][i] - m_i[rh][i]);  // <= e^8 deferred
                p1[rh][i] = __expf(p1[rh][i] - m_i[rh][i]);
                l_i[rh][i] += rowsum16(p0[rh][i] + p1[rh][i]);   // DPP, VALU-only
            }

        // P: C-layout -> A-layout via per-wave LDS (wave-local, no barrier)
        u16* Pw = Ps + wv * 1280;
        #pragma unroll
        for (int rh = 0; rh < 2; ++rh)
            #pragma unroll
            for (int i = 0; i < 4; ++i) {
                Pw[(rh * 16 + lq * 4 + i) * 40 + lm]      = f2b(p0[rh][i]);
                Pw[(rh * 16 + lq * 4 + i) * 40 + 16 + lm] = f2b(p1[rh][i]);
            }
        short8 pfrag0 = *(const short8*)(Pw + lm * 40 + lq * 8);
        short8 pfrag1 = *(const short8*)(Pw + (16 + lm) * 40 + lq * 8);

        if (need) {
            #pragma unroll
            for (int rh = 0; rh < 2; ++rh)
                #pragma unroll
                for (int nt = 0; nt < 8; ++nt)
                    #pragma unroll
                    for (int i = 0; i < 4; ++i) oacc[rh][nt][i] *= alpha[rh][i];
        }
        // O += P . V  (8 col-tiles of 16) — vfr shared by both rh
        #pragma unroll
        for (int nt = 0; nt < 8; ++nt) {
            int R = nt * 16 + lm;
            short8 vfr = *(const short8*)(Vc + swz(R, lq) * 8);
            oacc[0][nt] = __builtin_amdgcn_mfma_f32_16x16x32_bf16(
                pfrag0, vfr, oacc[0][nt], 0, 0, 0);
            oacc[1][nt] = __builtin_amdgcn_mfma_f32_16x16x32_bf16(
                pfrag1, vfr, oacc[1][nt], 0, 0, 0);
        }
    }

    #pragma unroll
    for (int rh = 0; rh < 2; ++rh) {
        int s0 = qt * 128 + wv * 32 + rh * 16 + lq * 4;
        #pragma unroll
        for (int i = 0; i < 4; ++i) {
            float inv = 1.f / l_i[rh][i];
            u16* dst = ctx_out + ((size_t)(bb * SEQ + s0 + i) * NH + h) * 128;
            #pragma unroll
            for (int nt = 0; nt < 8; ++nt)
                dst[nt * 16 + lm] = f2b(oacc[rh][nt][i] * inv);
        }
    }
}

// Fused dual-branch flash. Grid (NH, 16, NBATCH): x=h so all q-tiles of a
// head land on one XCD. 512 blocks = exactly 2/CU.
__global__ __launch_bounds__(256, 2)
void flash_fused(const u16* qf, const u16* kf, const u16* Vtg, u16* ctx,
                 const u16* pq, const u16* pk, const u16* pvt, u16* p_ctx,
                 float scale_main, float scale_pat)
{
    __shared__ __align__(16) u16 Ks[2 * 32 * DQ];    // 24 KB
    __shared__ __align__(16) u16 Vs[2 * 32 * 128];   // 16 KB
    __shared__ __align__(16) u16 Ps[4 * 32 * 40];    // 10 KB
    int h = blockIdx.x, qtb = blockIdx.y, bb = blockIdx.z;
    if (qtb < 8)
        flash_body<DQ>(qf, kf, Vtg, ctx, scale_main, Ks, Vs, Ps, qtb, h, bb);
    else
        flash_body<128>(pq, pk, pvt, p_ctx, scale_pat, Ks, Vs, Ps, qtb - 8, h, bb);
}

// ---------------------------------------------------------------------------
extern "C" void kernel_launch(void* const* d_in, const int* in_sizes, int n_in,
                              void* d_out, int out_size, void* d_ws, size_t ws_size,
                              hipStream_t stream)
{
    const float* X        = (const float*)d_in[0];
    const float* q_a_w    = (const float*)d_in[1];
    const float* q_a_ln_w = (const float*)d_in[2];
    const float* q_b_w    = (const float*)d_in[3];
    const float* kv_a_w   = (const float*)d_in[4];
    const float* kv_a_ln_w= (const float*)d_in[5];
    const float* kv_b_w   = (const float*)d_in[6];
    const float* o_w      = (const float*)d_in[7];
    const float* sp_q_w   = (const float*)d_in[8];
    const float* sp_k_w   = (const float*)d_in[9];
    const float* sp_v_w   = (const float*)d_in[10];
    const float* sp_o_w   = (const float*)d_in[11];
    const float* gate_w   = (const float*)d_in[12];
    const float* gate_b   = (const float*)d_in[13];
    float* out = (float*)d_out;

    // workspace carve (256B aligned)
    char* p = (char*)d_ws;
    auto alloc = [&](size_t bytes) -> char* {
        char* r = p; p += (bytes + 255) & ~(size_t)255; return r;
    };
    u16* amid      = (u16*)alloc((size_t)NTOK * 3072 * 2);       // bf16 [tok][q_mid|kv_a]
    u16* Xb        = (u16*)alloc((size_t)NTOK * HIDN * 2);
    u16* aw_b      = (u16*)alloc((size_t)3072 * HIDN * 2);       // [q_a_w; kv_a_w]
    u16* q_b_wb    = (u16*)alloc((size_t)NH * DQ * QRANK * 2);
    u16* kv_b_wb   = (u16*)alloc((size_t)NH * 256 * KVRANK * 2);
    u16* o_wb      = (u16*)alloc((size_t)HIDN * HIDN * 2);
    u16* spqkv_wb  = (u16*)alloc((size_t)3 * HIDN * HIDN * 2);   // [spq;spk;spv]
    u16* sp_o_wb   = (u16*)alloc((size_t)HIDN * HIDN * 2);
    u16* qf        = (u16*)alloc((size_t)NTOK * NH * DQ * 2);
    u16* kf        = (u16*)alloc((size_t)NTOK * NH * DQ * 2);
    u16* Vtg       = (u16*)alloc((size_t)NBATCH * NH * 128 * SEQ * 2);
    u16* pq        = (u16*)alloc((size_t)NTOK * HIDN * 2);
    u16* pk        = (u16*)alloc((size_t)NTOK * HIDN * 2);
    float* ssbuf   = (float*)alloc((size_t)2 * NTOK * 4);        // [ss_q | ss_kv]
    float2* gates  = (float2*)alloc((size_t)NTOK * 8);
    // aliases (stream-ordered disjoint lifetimes):
    u16* pvt    = aw_b;          // aw_b dead after amid GEMM; pvt written in mega
    u16* ctx    = q_b_wb;        // q_b_wb dead after mega; ctx written by flash
    u16* p_ctx  = spqkv_wb;      // spqkv_wb dead after mega; written by flash
    float* patout = (float*)qf;  // qf+kf dead after flash; 16.8MB
    float* ss_q  = ssbuf;
    float* ss_kv = ssbuf + NTOK;

    dim3 blk(256);

    // ---- 0. zero the sum-of-squares accumulators (graph-capture safe) ----
    hipMemsetAsync(ssbuf, 0, (size_t)2 * NTOK * 4, stream);

    // ---- 1. single fused cast dispatch (ln weights folded into q_b/kv_b) ----
    CastArgs ca;
    const float* srcs[10] = {X, q_a_w, kv_a_w, q_b_w, kv_b_w, o_w,
                             sp_q_w, sp_k_w, sp_v_w, sp_o_w};
    u16* dsts[10] = {Xb, aw_b, aw_b + (size_t)QRANK * HIDN, q_b_wb, kv_b_wb, o_wb,
                     spqkv_wb, spqkv_wb + (size_t)HIDN * HIDN,
                     spqkv_wb + (size_t)2 * HIDN * HIDN, sp_o_wb};
    int ns[10] = {NTOK * HIDN, QRANK * HIDN, 1536 * HIDN, NH * DQ * QRANK,
                  NH * 256 * KVRANK, HIDN * HIDN, HIDN * HIDN, HIDN * HIDN,
                  HIDN * HIDN, HIDN * HIDN};
    int cum = 0;
    for (int i = 0; i < 10; ++i) {
        ca.s[i] = srcs[i]; ca.d[i] = dsts[i];
        ca.cum[i] = cum; cum += ns[i] / 8;
    }
    ca.cum[10] = cum;
    ca.lnq = q_a_ln_w; ca.lnkv = kv_a_ln_w;
    cast_all<<<dim3((cum + 255) / 256), blk, 0, stream>>>(ca, cum);

    // ---- 2. gate logits (only needs X; off the tail critical path) ----
    gate_kern<<<dim3(NTOK), blk, 0, stream>>>(X, gate_w, gate_b, gates);

    // ---- 3. fused q_a + kv_a projection -> amid bf16 (+ row sumsq;
    //         k_pe panels rope directly into kf[...,128:192]) ----
    {
        GemmArgs ga = {};
        ga.nseg = 1;
        ga.seg[0] = {Xb, aw_b, nullptr, amid, kf, nullptr,
                     HIDN, HIDN, 3072, 5, 0};
        ga.ssq = ss_q; ga.sskv = ss_kv;
        gemm_multi<<<dim3(16, 24), blk, 0, stream>>>(ga);
    }

    // ---- 4. mega GEMM: sp_qkv | q_b (+inv_q, +RoPE) | kv_b (+inv_kv) ----
    {
        GemmArgs ga = {};
        ga.nseg = 3;
        ga.seg[0] = {Xb, spqkv_wb, nullptr, pq, pk, pvt,
                     HIDN, HIDN, 0, 4, 0};
        ga.seg[1] = {amid, q_b_wb, nullptr, qf, nullptr, nullptr,
                     QRANK, 3072, 0, 1, 48};
        ga.seg[2] = {amid + QRANK, kv_b_wb, nullptr, kf, Vtg, nullptr,
                     KVRANK, 3072, 0, 3, 72};
        ga.ssq = ss_q; ga.sskv = ss_kv;
        gemm_multi<<<dim3(16, 104), blk, 0, stream>>>(ga);
    }

    // ---- 5. fused dual flash attention (512 blocks, 2/CU, XCD-aligned) ----
    flash_fused<<<dim3(NH, 16, NBATCH), blk, 0, stream>>>(
        qf, kf, Vtg, ctx, pq, pk, pvt, p_ctx,
        1.0f / sqrtf((float)DQ), 1.0f / sqrtf(128.0f));

    // ---- 6. o-proj (g0-scaled -> out) + sp_o-proj (g1-scaled -> patout),
    //         two independent segments, plain stores, 512 blocks = 2/CU ----
    {
        GemmArgs ga = {};
        ga.nseg = 2;
        ga.seg[0] = {ctx, o_wb, out, nullptr, nullptr, nullptr,
                     HIDN, HIDN, 0, 6, 0};
        ga.seg[1] = {p_ctx, sp_o_wb, patout, nullptr, nullptr, nullptr,
                     HIDN, HIDN, 1, 6, 16};
        ga.gates = gates;
        gemm_multi<<<dim3(16, 32), blk, 0, stream>>>(ga);
    }

    // ---- 7. lean streaming combine: out += patout (50MB, ~9us) ----
    add_combine<<<dim3(1024), blk, 0, stream>>>(out, patout);
}